// Round 11
// baseline (87.384 us; speedup 1.0000x reference)
//
#include <hip/hip_runtime.h>

#define B_ 128
#define N_ 576
#define K_ 16
#define D_ 768
#define NC_ 1000
#define TCPAD 772  // 768 + 4 pad, float4-aligned LDS rows

// ---------------------------------------------------------------------------
// Kernel A: scores = img . (text[cls] + fine[cls,k]),  Qexp = exp(scores/eps)
// Grid: 6 blocks per b (96 rows each, 768 blocks), 512 threads (8 waves).
// Each wave: 3 rows per iteration (4 iters = 12 rows), TWO PASSES of 8 ks.
//
// TWO-PASS RATIONALE (round 11): t-read DS traffic depends only on R (48
// b128 per g-iter regardless of pass count), but acc regs halve: live set
// 24 acc + 12 x + 4 t + ~18 misc ~= 58 <= 64 VGPR -> 8 waves/SIMD, so the
// LDS cap (3 blocks/CU = 24 waves) finally binds WITH low DS traffic.
// Ladder: R=2 75.7 | R=4 73.2 | R=2+pf 78.0 | R=3(512,6) 86.9 | R=2@768 74.2.
//
// SPILL HISTORY (rounds 1,3,4,5 spilled 94-850 MB scratch): pre-RA scheduler
// hoists unrolled-j LDS loads above the FMA chain -> allocator spills accs.
// Fences (keep intact): (a) j-loop NOT unrolled (#pragma unroll 1),
// (b) sched_barrier(0) between 4-k chunks. No arrays/lambdas in hot path.
//
// BIT-IDENTITY: per (row,k) d-order (j asc, xyzw) unchanged; reduce masks
// 1,2,4 (k-bit splits), 8,16,32 (full), always local+received — identical FP
// sequence to the passing REDUCE16. Do not reorder: argmax near-ties amplify
// any rounding change into output-1 failures. Lane L holds total[(L&7)+koff].
// ---------------------------------------------------------------------------

#define ACC_K3(k, koff)                                                       \
  do {                                                                        \
    const float4 t =                                                          \
        *(const float4*)&tc[((k) + (koff)) * TCPAD + j * 256 + (lane << 2)];  \
    A0_##k += x0.x * t.x;                                                     \
    A0_##k += x0.y * t.y;                                                     \
    A0_##k += x0.z * t.z;                                                     \
    A0_##k += x0.w * t.w;                                                     \
    A1_##k += x1.x * t.x;                                                     \
    A1_##k += x1.y * t.y;                                                     \
    A1_##k += x1.z * t.z;                                                     \
    A1_##k += x1.w * t.w;                                                     \
    A2_##k += x2.x * t.x;                                                     \
    A2_##k += x2.y * t.y;                                                     \
    A2_##k += x2.z * t.z;                                                     \
    A2_##k += x2.w * t.w;                                                     \
  } while (0)

#define DECL_ACC8(P)                                                          \
  float P##0 = 0.f, P##1 = 0.f, P##2 = 0.f, P##3 = 0.f, P##4 = 0.f,           \
        P##5 = 0.f, P##6 = 0.f, P##7 = 0.f

// one butterfly step: combine (e=even-k, o=odd-k) into s, split on flag c
#define RSTEP(s, e, o, c, m)                        \
  do {                                              \
    const float kept_ = (c) ? (o) : (e);            \
    const float sent_ = (c) ? (e) : (o);            \
    s = kept_ + __shfl_xor(sent_, (m));             \
  } while (0)

// reduce-scatter over 8 named accumulators P##0..P##7 -> scalar out
// (masks 1,2,4 split on k-bits 0..2; 8,16,32 full: FP order == REDUCE16)
#define REDUCE8(out, P)                             \
  do {                                              \
    float S0, S1, S2, S3;                           \
    RSTEP(S0, P##0, P##1, c0, 1);                   \
    RSTEP(S1, P##2, P##3, c0, 1);                   \
    RSTEP(S2, P##4, P##5, c0, 1);                   \
    RSTEP(S3, P##6, P##7, c0, 1);                   \
    float T0, T1;                                   \
    RSTEP(T0, S0, S1, c1, 2);                       \
    RSTEP(T1, S2, S3, c1, 2);                       \
    float V;                                        \
    RSTEP(V, T0, T1, c2, 4);                        \
    V += __shfl_xor(V, 8);                          \
    V += __shfl_xor(V, 16);                         \
    V += __shfl_xor(V, 32);                         \
    out = V;                                        \
  } while (0)

// one 8-k pass over 3 rows; leaves v0..v2 = totals for k=(lane&7)+koff
#define PASS8(koff, vo0, vo1, vo2)                                            \
  do {                                                                        \
    DECL_ACC8(A0_);                                                           \
    DECL_ACC8(A1_);                                                           \
    DECL_ACC8(A2_);                                                           \
    _Pragma("unroll 1") for (int j = 0; j < 3; ++j) {                         \
      const float4 x0 = *(const float4*)&ib0[j * 256];                        \
      const float4 x1 = *(const float4*)&ib1[j * 256];                        \
      const float4 x2 = *(const float4*)&ib2[j * 256];                        \
      ACC_K3(0, koff);                                                        \
      ACC_K3(1, koff);                                                        \
      ACC_K3(2, koff);                                                        \
      ACC_K3(3, koff);                                                        \
      __builtin_amdgcn_sched_barrier(0);                                      \
      ACC_K3(4, koff);                                                        \
      ACC_K3(5, koff);                                                        \
      ACC_K3(6, koff);                                                        \
      ACC_K3(7, koff);                                                        \
    }                                                                         \
    REDUCE8(vo0, A0_);                                                        \
    REDUCE8(vo1, A1_);                                                        \
    REDUCE8(vo2, A2_);                                                        \
  } while (0)

__global__ __launch_bounds__(512, 8) void scores_exp_kernel(
    const float* __restrict__ img, const float* __restrict__ text,
    const float* __restrict__ fine, const int* __restrict__ target,
    float* __restrict__ fineL) {
  const int b = blockIdx.x / 6;
  const int chunk = blockIdx.x % 6;
  const int tid = threadIdx.x;
  const int cls = target[b];

  __shared__ float tc[K_ * TCPAD];

  // stage text_c[k][d] = text[cls][d] + fine[cls][k][d]  (float4, coalesced)
  for (int i = tid; i < (K_ * D_ / 4); i += 512) {
    const int k = i / (D_ / 4);
    const int d4 = i % (D_ / 4);
    const float4 t = *(const float4*)&text[(size_t)cls * D_ + d4 * 4];
    const float4 f = *(const float4*)&fine[((size_t)cls * K_ + k) * D_ + d4 * 4];
    *(float4*)&tc[k * TCPAD + d4 * 4] =
        make_float4(t.x + f.x, t.y + f.y, t.z + f.z, t.w + f.w);
  }
  __syncthreads();

  const int wave = tid >> 6;
  const int lane = tid & 63;
  const bool c0 = (lane & 1) != 0;
  const bool c1 = (lane & 2) != 0;
  const bool c2 = (lane & 4) != 0;

  for (int g = 0; g < 4; ++g) {
    const int row0 = chunk * 96 + wave * 12 + g * 3;

    const float* ib0 = img + ((size_t)b * N_ + row0) * D_ + (lane << 2);
    const float* ib1 = ib0 + D_;
    const float* ib2 = ib0 + 2 * D_;

    float vA0, vA1, vA2, vB0, vB1, vB2;
    PASS8(0, vA0, vA1, vA2);
    PASS8(8, vB0, vB1, vB2);

    if (lane < 8) {
      float* o0 = &fineL[((size_t)b * N_ + row0) * K_ + lane];
      o0[0] = expf(vA0 / 0.05f);
      o0[8] = expf(vB0 / 0.05f);
      o0[K_] = expf(vA1 / 0.05f);
      o0[K_ + 8] = expf(vB1 / 0.05f);
      o0[2 * K_] = expf(vA2 / 0.05f);
      o0[2 * K_ + 8] = expf(vB2 / 0.05f);
    }
  }
}

// ---------------------------------------------------------------------------
// Kernel B: per-b Sinkhorn (3 iters) + argmax + outputs.
// One block per b, 576 threads (9 waves); thread n holds Q[:,n] (16 regs).
// Mirrors the reference normalization sequence with true f32 divisions.
// ---------------------------------------------------------------------------
__global__ __launch_bounds__(576) void sinkhorn_kernel(
    float* __restrict__ fineL, float* __restrict__ fineT,
    const int* __restrict__ target) {
  const int b = blockIdx.x;
  const int n = threadIdx.x;
  const int lane = n & 63;
  const int wave = n >> 6;

  __shared__ float red[9 * 16];

  float q[16];
  float4* rowp = (float4*)&fineL[((size_t)b * N_ + n) * K_];
  {
    const float4 a0 = rowp[0], a1 = rowp[1], a2 = rowp[2], a3 = rowp[3];
    q[0] = a0.x; q[1] = a0.y; q[2] = a0.z; q[3] = a0.w;
    q[4] = a1.x; q[5] = a1.y; q[6] = a1.z; q[7] = a1.w;
    q[8] = a2.x; q[9] = a2.y; q[10] = a2.z; q[11] = a2.w;
    q[12] = a3.x; q[13] = a3.y; q[14] = a3.z; q[15] = a3.w;
  }

  // global sum over (k, n) for this b
  float s = 0.0f;
#pragma unroll
  for (int k = 0; k < 16; ++k) s += q[k];
  s += __shfl_xor(s, 1);
  s += __shfl_xor(s, 2);
  s += __shfl_xor(s, 4);
  s += __shfl_xor(s, 8);
  s += __shfl_xor(s, 16);
  s += __shfl_xor(s, 32);
  if (lane == 0) red[wave] = s;
  __syncthreads();
  float S = 0.0f;
#pragma unroll
  for (int w = 0; w < 9; ++w) S += red[w];
#pragma unroll
  for (int k = 0; k < 16; ++k) q[k] = q[k] / S;

  for (int it = 0; it < 3; ++it) {
    __syncthreads();  // protect red before rewriting
    // row sums (over n) for each k
#pragma unroll
    for (int k = 0; k < 16; ++k) {
      float v = q[k];
      v += __shfl_xor(v, 1);
      v += __shfl_xor(v, 2);
      v += __shfl_xor(v, 4);
      v += __shfl_xor(v, 8);
      v += __shfl_xor(v, 16);
      v += __shfl_xor(v, 32);
      if (lane == 0) red[wave * 16 + k] = v;
    }
    __syncthreads();
#pragma unroll
    for (int k = 0; k < 16; ++k) {
      float r = 0.0f;
#pragma unroll
      for (int w = 0; w < 9; ++w) r += red[w * 16 + k];
      q[k] = q[k] / (r * 16.0f);
    }
    // column normalize (per-thread, no communication)
    float c = 0.0f;
#pragma unroll
    for (int k = 0; k < 16; ++k) c += q[k];
    const float cd = c * 576.0f;
#pragma unroll
    for (int k = 0; k < 16; ++k) q[k] = q[k] / cd;
  }

#pragma unroll
  for (int k = 0; k < 16; ++k) q[k] *= 576.0f;

  // argmax (strict >, first occurrence wins — matches jnp.argmax)
  int best = 0;
  float bv = q[0];
#pragma unroll
  for (int k = 1; k < 16; ++k)
    if (q[k] > bv) { bv = q[k]; best = k; }

  rowp[0] = make_float4(q[0], q[1], q[2], q[3]);
  rowp[1] = make_float4(q[4], q[5], q[6], q[7]);
  rowp[2] = make_float4(q[8], q[9], q[10], q[11]);
  rowp[3] = make_float4(q[12], q[13], q[14], q[15]);
  fineT[(size_t)b * N_ + n] = (float)(best * NC_ + target[b]);
}

extern "C" void kernel_launch(void* const* d_in, const int* in_sizes, int n_in,
                              void* d_out, int out_size, void* d_ws, size_t ws_size,
                              hipStream_t stream) {
  const float* img = (const float*)d_in[0];
  const float* text = (const float*)d_in[1];
  const float* fine = (const float*)d_in[2];
  const int* target = (const int*)d_in[3];

  float* fineL = (float*)d_out;                          // [B][N][K] f32
  float* fineT = (float*)d_out + (size_t)B_ * N_ * K_;   // [B*N] as f32

  scores_exp_kernel<<<B_ * 6, 512, 0, stream>>>(img, text, fine, target, fineL);
  sinkhorn_kernel<<<B_, 576, 0, stream>>>(fineL, fineT, target);
}

// Round 12
// 72.256 us; speedup vs baseline: 1.2094x; 1.2094x over previous
//
#include <hip/hip_runtime.h>

#define B_ 128
#define N_ 576
#define K_ 16
#define D_ 768
#define NC_ 1000
#define TCPAD 772  // 768 + 4 pad, float4-aligned LDS rows

// ---------------------------------------------------------------------------
// Kernel A: scores = img . (text[cls] + fine[cls,k]),  Qexp = exp(scores/eps)
// Grid: 6 blocks per b (96 rows each), 512 threads (8 waves).
// Each wave: 4 rows per iteration (3 iters = 12 rows), full-wave split over D.
// BEST MEASURED CONFIG (round 7: 73.2us). Full ladder probed: R=2 75.7 |
// R=4 73.2 | R=2+prefetch 78.0 | R=3 86.9 | R=2@768blk 74.2 | R=3/2pass 87.4.
// Geometry/occupancy levers are exhausted — all configs cluster ~73-87; this
// is the plateau point. Do not re-probe geometry without a new mechanism.
//
// SPILL HISTORY (rounds 1,3,4,5 spilled 94-850 MB scratch): root cause is the
// pre-RA scheduler hoisting unrolled-j LDS loads above the FMA chain, then
// the allocator spills accumulators. Round 6 fix (636->75.7us, keep intact):
// (a) j-loop NOT unrolled (#pragma unroll 1 — backedge blocks hoisting),
// (b) sched_barrier(0) between 4-k chunks bounds the window,
// (c) launch_bounds(512,4) gives the allocator headroom.
// Do not re-unroll j; do not remove barriers; no arrays/lambdas in hot path.
//
// Reduction tree order (xor1 by k-bit0, xor2, xor4, xor8, then xor16/32) is
// BIT-IDENTICAL to the passing round-1 butterfly — do not reorder: argmax
// near-ties amplify any rounding change into output-1 failures.
// Lane L ends holding total[k = L & 15].
// ---------------------------------------------------------------------------

#define ACC_K(k)                                                              \
  do {                                                                        \
    const float4 t = *(const float4*)&tc[(k)*TCPAD + j * 256 + (lane << 2)];  \
    A0_##k += x0.x * t.x;                                                     \
    A0_##k += x0.y * t.y;                                                     \
    A0_##k += x0.z * t.z;                                                     \
    A0_##k += x0.w * t.w;                                                     \
    A1_##k += x1.x * t.x;                                                     \
    A1_##k += x1.y * t.y;                                                     \
    A1_##k += x1.z * t.z;                                                     \
    A1_##k += x1.w * t.w;                                                     \
    A2_##k += x2.x * t.x;                                                     \
    A2_##k += x2.y * t.y;                                                     \
    A2_##k += x2.z * t.z;                                                     \
    A2_##k += x2.w * t.w;                                                     \
    A3_##k += x3.x * t.x;                                                     \
    A3_##k += x3.y * t.y;                                                     \
    A3_##k += x3.z * t.z;                                                     \
    A3_##k += x3.w * t.w;                                                     \
  } while (0)

#define DECL_ACC(P)                                                           \
  float P##0 = 0.f, P##1 = 0.f, P##2 = 0.f, P##3 = 0.f, P##4 = 0.f,           \
        P##5 = 0.f, P##6 = 0.f, P##7 = 0.f, P##8 = 0.f, P##9 = 0.f,           \
        P##10 = 0.f, P##11 = 0.f, P##12 = 0.f, P##13 = 0.f, P##14 = 0.f,      \
        P##15 = 0.f

// one butterfly step: combine (e=even-k, o=odd-k) into s, split on flag c
#define RSTEP(s, e, o, c, m)                        \
  do {                                              \
    const float kept_ = (c) ? (o) : (e);            \
    const float sent_ = (c) ? (e) : (o);            \
    s = kept_ + __shfl_xor(sent_, (m));             \
  } while (0)

// full reduce-scatter over 16 named accumulators P##0..P##15 -> scalar out
#define REDUCE16(out, P)                            \
  do {                                              \
    float S0, S1, S2, S3, S4, S5, S6, S7;           \
    RSTEP(S0, P##0, P##1, c0, 1);                   \
    RSTEP(S1, P##2, P##3, c0, 1);                   \
    RSTEP(S2, P##4, P##5, c0, 1);                   \
    RSTEP(S3, P##6, P##7, c0, 1);                   \
    RSTEP(S4, P##8, P##9, c0, 1);                   \
    RSTEP(S5, P##10, P##11, c0, 1);                 \
    RSTEP(S6, P##12, P##13, c0, 1);                 \
    RSTEP(S7, P##14, P##15, c0, 1);                 \
    float T0, T1, T2, T3;                           \
    RSTEP(T0, S0, S1, c1, 2);                       \
    RSTEP(T1, S2, S3, c1, 2);                       \
    RSTEP(T2, S4, S5, c1, 2);                       \
    RSTEP(T3, S6, S7, c1, 2);                       \
    float U0, U1;                                   \
    RSTEP(U0, T0, T1, c2, 4);                       \
    RSTEP(U1, T2, T3, c2, 4);                       \
    float V;                                        \
    RSTEP(V, U0, U1, c3, 8);                        \
    V += __shfl_xor(V, 16);                         \
    V += __shfl_xor(V, 32);                         \
    out = V;                                        \
  } while (0)

__global__ __launch_bounds__(512, 4) void scores_exp_kernel(
    const float* __restrict__ img, const float* __restrict__ text,
    const float* __restrict__ fine, const int* __restrict__ target,
    float* __restrict__ fineL) {
  const int b = blockIdx.x / 6;
  const int chunk = blockIdx.x % 6;
  const int tid = threadIdx.x;
  const int cls = target[b];

  __shared__ float tc[K_ * TCPAD];

  // stage text_c[k][d] = text[cls][d] + fine[cls][k][d]  (float4, coalesced)
  for (int i = tid; i < (K_ * D_ / 4); i += 512) {
    const int k = i / (D_ / 4);
    const int d4 = i % (D_ / 4);
    const float4 t = *(const float4*)&text[(size_t)cls * D_ + d4 * 4];
    const float4 f = *(const float4*)&fine[((size_t)cls * K_ + k) * D_ + d4 * 4];
    *(float4*)&tc[k * TCPAD + d4 * 4] =
        make_float4(t.x + f.x, t.y + f.y, t.z + f.z, t.w + f.w);
  }
  __syncthreads();

  const int wave = tid >> 6;
  const int lane = tid & 63;
  const bool c0 = (lane & 1) != 0;
  const bool c1 = (lane & 2) != 0;
  const bool c2 = (lane & 4) != 0;
  const bool c3 = (lane & 8) != 0;

  for (int g = 0; g < 3; ++g) {
    const int row0 = chunk * 96 + wave * 12 + g * 4;

    DECL_ACC(A0_);
    DECL_ACC(A1_);
    DECL_ACC(A2_);
    DECL_ACC(A3_);

    const float* ib0 = img + ((size_t)b * N_ + row0) * D_ + (lane << 2);
    const float* ib1 = ib0 + D_;
    const float* ib2 = ib0 + 2 * D_;
    const float* ib3 = ib0 + 3 * D_;

#pragma unroll 1
    for (int j = 0; j < 3; ++j) {
      const float4 x0 = *(const float4*)&ib0[j * 256];
      const float4 x1 = *(const float4*)&ib1[j * 256];
      const float4 x2 = *(const float4*)&ib2[j * 256];
      const float4 x3 = *(const float4*)&ib3[j * 256];
      ACC_K(0);
      ACC_K(1);
      ACC_K(2);
      ACC_K(3);
      __builtin_amdgcn_sched_barrier(0);
      ACC_K(4);
      ACC_K(5);
      ACC_K(6);
      ACC_K(7);
      __builtin_amdgcn_sched_barrier(0);
      ACC_K(8);
      ACC_K(9);
      ACC_K(10);
      ACC_K(11);
      __builtin_amdgcn_sched_barrier(0);
      ACC_K(12);
      ACC_K(13);
      ACC_K(14);
      ACC_K(15);
    }

    float v0, v1, v2, v3;
    REDUCE16(v0, A0_);
    REDUCE16(v1, A1_);
    REDUCE16(v2, A2_);
    REDUCE16(v3, A3_);
    if (lane < 16) {
      fineL[((size_t)b * N_ + row0) * K_ + lane] = expf(v0 / 0.05f);
      fineL[((size_t)b * N_ + row0 + 1) * K_ + lane] = expf(v1 / 0.05f);
      fineL[((size_t)b * N_ + row0 + 2) * K_ + lane] = expf(v2 / 0.05f);
      fineL[((size_t)b * N_ + row0 + 3) * K_ + lane] = expf(v3 / 0.05f);
    }
  }
}

// ---------------------------------------------------------------------------
// Kernel B: per-b Sinkhorn (3 iters) + argmax + outputs.
// One block per b, 576 threads (9 waves); thread n holds Q[:,n] (16 regs).
// Mirrors the reference normalization sequence with true f32 divisions.
// ---------------------------------------------------------------------------
__global__ __launch_bounds__(576) void sinkhorn_kernel(
    float* __restrict__ fineL, float* __restrict__ fineT,
    const int* __restrict__ target) {
  const int b = blockIdx.x;
  const int n = threadIdx.x;
  const int lane = n & 63;
  const int wave = n >> 6;

  __shared__ float red[9 * 16];

  float q[16];
  float4* rowp = (float4*)&fineL[((size_t)b * N_ + n) * K_];
  {
    const float4 a0 = rowp[0], a1 = rowp[1], a2 = rowp[2], a3 = rowp[3];
    q[0] = a0.x; q[1] = a0.y; q[2] = a0.z; q[3] = a0.w;
    q[4] = a1.x; q[5] = a1.y; q[6] = a1.z; q[7] = a1.w;
    q[8] = a2.x; q[9] = a2.y; q[10] = a2.z; q[11] = a2.w;
    q[12] = a3.x; q[13] = a3.y; q[14] = a3.z; q[15] = a3.w;
  }

  // global sum over (k, n) for this b
  float s = 0.0f;
#pragma unroll
  for (int k = 0; k < 16; ++k) s += q[k];
  s += __shfl_xor(s, 1);
  s += __shfl_xor(s, 2);
  s += __shfl_xor(s, 4);
  s += __shfl_xor(s, 8);
  s += __shfl_xor(s, 16);
  s += __shfl_xor(s, 32);
  if (lane == 0) red[wave] = s;
  __syncthreads();
  float S = 0.0f;
#pragma unroll
  for (int w = 0; w < 9; ++w) S += red[w];
#pragma unroll
  for (int k = 0; k < 16; ++k) q[k] = q[k] / S;

  for (int it = 0; it < 3; ++it) {
    __syncthreads();  // protect red before rewriting
    // row sums (over n) for each k
#pragma unroll
    for (int k = 0; k < 16; ++k) {
      float v = q[k];
      v += __shfl_xor(v, 1);
      v += __shfl_xor(v, 2);
      v += __shfl_xor(v, 4);
      v += __shfl_xor(v, 8);
      v += __shfl_xor(v, 16);
      v += __shfl_xor(v, 32);
      if (lane == 0) red[wave * 16 + k] = v;
    }
    __syncthreads();
#pragma unroll
    for (int k = 0; k < 16; ++k) {
      float r = 0.0f;
#pragma unroll
      for (int w = 0; w < 9; ++w) r += red[w * 16 + k];
      q[k] = q[k] / (r * 16.0f);
    }
    // column normalize (per-thread, no communication)
    float c = 0.0f;
#pragma unroll
    for (int k = 0; k < 16; ++k) c += q[k];
    const float cd = c * 576.0f;
#pragma unroll
    for (int k = 0; k < 16; ++k) q[k] = q[k] / cd;
  }

#pragma unroll
  for (int k = 0; k < 16; ++k) q[k] *= 576.0f;

  // argmax (strict >, first occurrence wins — matches jnp.argmax)
  int best = 0;
  float bv = q[0];
#pragma unroll
  for (int k = 1; k < 16; ++k)
    if (q[k] > bv) { bv = q[k]; best = k; }

  rowp[0] = make_float4(q[0], q[1], q[2], q[3]);
  rowp[1] = make_float4(q[4], q[5], q[6], q[7]);
  rowp[2] = make_float4(q[8], q[9], q[10], q[11]);
  rowp[3] = make_float4(q[12], q[13], q[14], q[15]);
  fineT[(size_t)b * N_ + n] = (float)(best * NC_ + target[b]);
}

extern "C" void kernel_launch(void* const* d_in, const int* in_sizes, int n_in,
                              void* d_out, int out_size, void* d_ws, size_t ws_size,
                              hipStream_t stream) {
  const float* img = (const float*)d_in[0];
  const float* text = (const float*)d_in[1];
  const float* fine = (const float*)d_in[2];
  const int* target = (const int*)d_in[3];

  float* fineL = (float*)d_out;                          // [B][N][K] f32
  float* fineT = (float*)d_out + (size_t)B_ * N_ * K_;   // [B*N] as f32

  scores_exp_kernel<<<B_ * 6, 512, 0, stream>>>(img, text, fine, target, fineL);
  sinkhorn_kernel<<<B_, 576, 0, stream>>>(fineL, fineT, target);
}